// Round 3
// baseline (419.128 us; speedup 1.0000x reference)
//
#include <hip/hip_runtime.h>
#include <hip/hip_cooperative_groups.h>
namespace cg = cooperative_groups;

// Problem constants (complete bipartite proxy<->sample + self-loops)
#define PP 100    // proxies
#define NS 1024   // samples
#define NN 1124   // total nodes
#define DD 512    // feature dim
#define CC 100    // fc out dim
#define NTHR 256

typedef _Float16 f16;
typedef _Float16 f16x8 __attribute__((ext_vector_type(8)));
typedef float    f32x4 __attribute__((ext_vector_type(4)));

__device__ __forceinline__ float lk(float v) { return v > 0.f ? v : 0.2f * v; }
__device__ __forceinline__ f16 hif(float v) { return (f16)v; }
__device__ __forceinline__ f16 lof(float v) { return (f16)(v - (float)((f16)v)); }

// All pointers bundled so the fused kernel takes one kernarg struct.
struct FA {
  const float *x, *prox, *W1, *as1, *ad1, *b1, *W2, *as2, *ad2, *b2, *fcw, *fcb;
  float *out, *h1, *ls1, *ld1, *ls2, *ld2, *v1s, *v1d, *v2s, *v2d;
  float *esS1, *izS1, *esS2, *izS2, *esP, *izP, *h2s;
  f16 *M1h, *M1l, *M2h, *M2l, *Es1h, *Es1l, *Es2h, *Es2l, *Eph, *Epl;
  f16 *xth, *xtl, *pth, *ptl, *W1th, *W1tl, *W2th, *W2tl, *fwth, *fwtl;
  f16 *h2h, *h2l, *h1pth, *h1ptl;
};

// =================== MFMA split-f16 GEMM core =============================
// acc[2][2] += A[row0.., K] @ B  where A given as (Ah,Al) row-major [*,K],
// B given TRANSPOSED as (Bth,Btl) row-major [*,K] (row = output col).
// Block tile 64x64, 4 waves of 32x32 (2x2 frags 16x16), BK=32, K % 32 == 0.
// C = Ah*Bh + Al*Bh + Ah*Bl  (split-f16, fp32 accumulate; al*bl dropped).
// lds: f16[4*64*40] (rows padded to 40 halves -> 16B-aligned, spread banks).
__device__ __forceinline__ void mgemm_core(
    const f16* __restrict__ Ah, const f16* __restrict__ Al,
    const f16* __restrict__ Bth, const f16* __restrict__ Btl,
    int K, int row0, int col0, f16* __restrict__ lds, f32x4 acc[2][2])
{
  const int t = threadIdx.x;
  const int lane = t & 63, w = t >> 6;
  const int wr = w >> 1, wc = w & 1;
  f16* Ash = lds;
  f16* Asl = lds + 2560;
  f16* Bsh = lds + 5120;
  f16* Bsl = lds + 7680;
  const int srow = t >> 2, su = t & 3;                 // staging: row, 8-half unit
  const size_t aoff = (size_t)(row0 + srow) * K + su * 8;
  const size_t boff = (size_t)(col0 + srow) * K + su * 8;
  const int lw = srow * 40 + su * 8;
  f32x4 pa0 = *(const f32x4*)(Ah + aoff);
  f32x4 pa1 = *(const f32x4*)(Al + aoff);
  f32x4 pb0 = *(const f32x4*)(Bth + boff);
  f32x4 pb1 = *(const f32x4*)(Btl + boff);
  const int fra = wr * 32 + (lane & 15);               // A frag row (local)
  const int frb = wc * 32 + (lane & 15);               // B frag col (local)
  const int fu  = (lane >> 4) * 8;                     // k offset within BK
  for (int kt = 32; kt <= K; kt += 32) {
    *(f32x4*)(Ash + lw) = pa0;
    *(f32x4*)(Asl + lw) = pa1;
    *(f32x4*)(Bsh + lw) = pb0;
    *(f32x4*)(Bsl + lw) = pb1;
    __syncthreads();
    if (kt < K) {                                      // prefetch next tile
      pa0 = *(const f32x4*)(Ah + aoff + kt);
      pa1 = *(const f32x4*)(Al + aoff + kt);
      pb0 = *(const f32x4*)(Bth + boff + kt);
      pb1 = *(const f32x4*)(Btl + boff + kt);
    }
    f16x8 ah[2], al[2], bh[2], bl[2];
#pragma unroll
    for (int m = 0; m < 2; ++m) {
      ah[m] = *(const f16x8*)(Ash + (fra + m * 16) * 40 + fu);
      al[m] = *(const f16x8*)(Asl + (fra + m * 16) * 40 + fu);
    }
#pragma unroll
    for (int n = 0; n < 2; ++n) {
      bh[n] = *(const f16x8*)(Bsh + (frb + n * 16) * 40 + fu);
      bl[n] = *(const f16x8*)(Bsl + (frb + n * 16) * 40 + fu);
    }
#pragma unroll
    for (int m = 0; m < 2; ++m)
#pragma unroll
      for (int n = 0; n < 2; ++n) {
        acc[m][n] = __builtin_amdgcn_mfma_f32_16x16x32_f16(ah[m], bh[n], acc[m][n], 0, 0, 0);
        acc[m][n] = __builtin_amdgcn_mfma_f32_16x16x32_f16(al[m], bh[n], acc[m][n], 0, 0, 0);
        acc[m][n] = __builtin_amdgcn_mfma_f32_16x16x32_f16(ah[m], bl[n], acc[m][n], 0, 0, 0);
      }
    __syncthreads();
  }
}

// C/D frag mapping (HW-verified): col = lane&15, row = (lane>>4)*4 + q.

// ======== 64x64 transpose+split tile (fp32 in -> f16 hi/lo transposed) =====
__device__ __forceinline__ void cvt_tile(
    const float* __restrict__ in, int R, int Cin,
    f16* __restrict__ oh, f16* __restrict__ ol, int ldo,
    int ti, int tj, f16 (*th)[72], f16 (*tl)[72])
{
  const int t = threadIdx.x;
#pragma unroll
  for (int p = 0; p < 4; ++p) {
    const int f = t + p * 256;
    const int i = f >> 4, j4 = (f & 15) * 4;
    const int gi = ti * 64 + i, gj = tj * 64 + j4;
    float4 v = make_float4(0.f, 0.f, 0.f, 0.f);
    if (gi < R && gj + 3 < Cin) v = *(const float4*)(in + (size_t)gi * Cin + gj);
    th[i][j4 + 0] = hif(v.x); tl[i][j4 + 0] = lof(v.x);
    th[i][j4 + 1] = hif(v.y); tl[i][j4 + 1] = lof(v.y);
    th[i][j4 + 2] = hif(v.z); tl[i][j4 + 2] = lof(v.z);
    th[i][j4 + 3] = hif(v.w); tl[i][j4 + 3] = lof(v.w);
  }
  __syncthreads();
#pragma unroll
  for (int p = 0; p < 2; ++p) {
    const int f = t + p * 256;
    const int j = f >> 3, i8 = (f & 7) * 8;
    f16x8 vh, vl;
#pragma unroll
    for (int e = 0; e < 8; ++e) { vh[e] = th[i8 + e][j]; vl[e] = tl[i8 + e][j]; }
    const size_t o = (size_t)(tj * 64 + j) * ldo + ti * 64 + i8;
    *(f16x8*)(oh + o) = vh;
    *(f16x8*)(ol + o) = vl;
  }
}

// ===== phase bodies (shared by fused kernel and fallback wrappers) =========

// prep: u in [0,544). transposes/splits + weight-side matvecs.
__device__ void dv_prep(int u, const FA& a, f16 (*th)[72], f16 (*tl)[72])
{
  if (u < 64) {
    cvt_tile(a.W1, 512, 512, a.W1th, a.W1tl, 512, u >> 3, u & 7, th, tl);
  } else if (u < 128) {
    cvt_tile(a.W2, 512, 512, a.W2th, a.W2tl, 512, (u - 64) >> 3, (u - 64) & 7, th, tl);
  } else if (u < 256) {
    cvt_tile(a.x, NS, 512, a.xth, a.xtl, NS, (u - 128) >> 3, (u - 128) & 7, th, tl);
  } else if (u < 272) {
    cvt_tile(a.prox, PP, 512, a.pth, a.ptl, 128, (u - 256) >> 3, (u - 256) & 7, th, tl);
  } else if (u < 288) {
    cvt_tile(a.fcw, 512, CC, a.fwth, a.fwtl, 512, (u - 272) >> 1, (u - 272) & 1, th, tl);
  } else {
    const int wid  = (u - 288) * 4 + (threadIdx.x >> 6);   // 0..1023
    const int lane = threadIdx.x & 63;
    const int r = wid & 511;
    const bool l1 = (wid < 512);
    const float* W = l1 ? a.W1 : a.W2;
    const float4* a4 = (const float4*)(l1 ? a.as1 : a.as2);
    const float4* b4 = (const float4*)(l1 ? a.ad1 : a.ad2);
    const float4* w4 = (const float4*)(W + (size_t)r * DD);
    float4 w0 = w4[lane], w1 = w4[lane + 64];
    float4 a0 = a4[lane], a1 = a4[lane + 64];
    float4 b0 = b4[lane], b1 = b4[lane + 64];
    float s1 = w0.x * a0.x + w0.y * a0.y + w0.z * a0.z + w0.w * a0.w
             + w1.x * a1.x + w1.y * a1.y + w1.z * a1.z + w1.w * a1.w;
    float s2 = w0.x * b0.x + w0.y * b0.y + w0.z * b0.z + w0.w * b0.w
             + w1.x * b1.x + w1.y * b1.y + w1.z * b1.z + w1.w * b1.w;
#pragma unroll
    for (int off = 32; off > 0; off >>= 1) {
      s1 += __shfl_down(s1, off);
      s2 += __shfl_down(s2, off);
    }
    if (lane == 0) {
      (l1 ? a.v1s : a.v2s)[r] = s1;
      (l1 ? a.v1d : a.v2d)[r] = s2;
    }
  }
}

// logits: ls[r]=row_r.vs, ld[r]=row_r.vd (one wave per row; u in [0,281))
__device__ void dv_lvec(int u, const float* A0, const float* A1, int split,
                        const float* vs, const float* vd, float* ls, float* ld)
{
  const int r    = u * 4 + (threadIdx.x >> 6);
  const int lane = threadIdx.x & 63;
  if (r >= NN) return;
  const float* row = (r < split) ? A0 + (size_t)r * DD : A1 + (size_t)(r - split) * DD;
  const float4* r4 = (const float4*)row;
  const float4* s4 = (const float4*)vs;
  const float4* d4 = (const float4*)vd;
  float4 v0 = r4[lane], v1 = r4[lane + 64];
  float4 a0 = s4[lane], a1 = s4[lane + 64];
  float4 b0 = d4[lane], b1 = d4[lane + 64];
  float s1 = v0.x * a0.x + v0.y * a0.y + v0.z * a0.z + v0.w * a0.w
           + v1.x * a1.x + v1.y * a1.y + v1.z * a1.z + v1.w * a1.w;
  float s2 = v0.x * b0.x + v0.y * b0.y + v0.z * b0.z + v0.w * b0.w
           + v1.x * b1.x + v1.y * b1.y + v1.z * b1.z + v1.w * b1.w;
#pragma unroll
  for (int off = 32; off > 0; off >>= 1) {
    s1 += __shfl_down(s1, off);
    s2 += __shfl_down(s2, off);
  }
  if (lane == 0) { ls[r] = s1; ld[r] = s2; }
}

// softmax weights -> split f16. u in [0,384): [0,256) sample quads,
// [256,384) proxy rows (i >= PP rows zero-fill the Ep k-pad).
__device__ void dv_alpha(int u, const float* ls, const float* ld,
                         f16* Esh, f16* Esl, float* esS, float* izS,
                         f16* Eph, f16* Epl, float* esP, float* izP, float* red)
{
  const int t = threadIdx.x;
  if (u < 256) {
    const int lane = t & 63;
    const int i = u * 4 + (t >> 6);              // sample dst
    const float ldi = ld[PP + i];
    float e0 = lk(ls[lane] + ldi);               // lane < 100 always
    float e1 = (lane < PP - 64) ? lk(ls[lane + 64] + ldi) : -1e30f;
    const float eself = lk(ls[PP + i] + ldi);
    float m = fmaxf(fmaxf(e0, e1), eself);
#pragma unroll
    for (int off = 1; off < 64; off <<= 1) m = fmaxf(m, __shfl_xor(m, off));
    float x0 = __expf(e0 - m);
    float x1 = (lane < PP - 64) ? __expf(e1 - m) : 0.f;
    float z = x0 + x1;
#pragma unroll
    for (int off = 1; off < 64; off <<= 1) z += __shfl_xor(z, off);
    Esh[(size_t)i * 128 + lane]      = hif(x0);
    Esl[(size_t)i * 128 + lane]      = lof(x0);
    Esh[(size_t)i * 128 + 64 + lane] = hif(x1);
    Esl[(size_t)i * 128 + 64 + lane] = lof(x1);
    if (lane == 0) {
      float xs = __expf(eself - m);
      esS[i] = xs;
      izS[i] = 1.f / (z + xs);
    }
  } else {
    const int i = u - 256;                       // proxy dst (or k-pad row)
    if (i >= PP) {                               // zero-fill pad rows 100..127
#pragma unroll
      for (int q = 0; q < 4; ++q) {
        Eph[(size_t)i * NS + t + q * 256] = (f16)0.f;
        Epl[(size_t)i * NS + t + q * 256] = (f16)0.f;
      }
      return;
    }
    const float ldi = ld[i];
    const float eself = lk(ls[i] + ldi);
    float e[4];
#pragma unroll
    for (int q = 0; q < 4; ++q) e[q] = lk(ls[PP + t + q * 256] + ldi);
    float m = fmaxf(fmaxf(fmaxf(e[0], e[1]), fmaxf(e[2], e[3])), eself);
#pragma unroll
    for (int off = 1; off < 64; off <<= 1) m = fmaxf(m, __shfl_xor(m, off));
    if ((t & 63) == 0) red[t >> 6] = m;
    __syncthreads();
    m = fmaxf(fmaxf(red[0], red[1]), fmaxf(red[2], red[3]));
    __syncthreads();
    float xq[4], z = 0.f;
#pragma unroll
    for (int q = 0; q < 4; ++q) { xq[q] = __expf(e[q] - m); z += xq[q]; }
#pragma unroll
    for (int off = 1; off < 64; off <<= 1) z += __shfl_xor(z, off);
    if ((t & 63) == 0) red[t >> 6] = z;
    __syncthreads();
#pragma unroll
    for (int q = 0; q < 4; ++q) {
      Eph[(size_t)i * NS + t + q * 256] = hif(xq[q]);
      Epl[(size_t)i * NS + t + q * 256] = lof(xq[q]);
    }
    if (t == 0) {
      float xs = __expf(eself - m);
      esP[i] = xs;
      izP[i] = 1.f / (red[0] + red[1] + red[2] + red[3] + xs);
    }
  }
}

// layer-1 aggregation: u in [0,144): [0,128) sample tiles, [128,144) proxy.
__device__ void dv_agg1(int u, const FA& a, f16* lds)
{
  f32x4 acc[2][2] = {};
  const int t = threadIdx.x, lane = t & 63, w = t >> 6, wr = w >> 1, wc = w & 1;
  if (u < 128) {
    // M1_samp[1024,512] = Es1[1024,128] @ prox(pad 128), epi self = x
    const int row0 = (u >> 3) * 64, col0 = (u & 7) * 64;
    mgemm_core(a.Es1h, a.Es1l, a.pth, a.ptl, 128, row0, col0, lds, acc);
#pragma unroll
    for (int m = 0; m < 2; ++m)
#pragma unroll
      for (int q = 0; q < 4; ++q) {
        const int r = row0 + wr * 32 + m * 16 + (lane >> 4) * 4 + q;
        const float e = a.esS1[r], z = a.izS1[r];
#pragma unroll
        for (int n = 0; n < 2; ++n) {
          const int c = col0 + wc * 32 + n * 16 + (lane & 15);
          const float v = (acc[m][n][q] + e * a.x[(size_t)r * DD + c]) * z;
          const size_t o = (size_t)(PP + r) * DD + c;
          a.M1h[o] = hif(v); a.M1l[o] = lof(v);
        }
      }
  } else {
    // M1_prox[100,512] = Ep[100(pad128),1024] @ x, epi self = prox
    const int b2 = u - 128;
    const int row0 = (b2 >> 3) * 64, col0 = (b2 & 7) * 64;
    mgemm_core(a.Eph, a.Epl, a.xth, a.xtl, NS, row0, col0, lds, acc);
#pragma unroll
    for (int m = 0; m < 2; ++m)
#pragma unroll
      for (int q = 0; q < 4; ++q) {
        const int r = row0 + wr * 32 + m * 16 + (lane >> 4) * 4 + q;
        if (r < PP) {
          const float e = a.esP[r], z = a.izP[r];
#pragma unroll
          for (int n = 0; n < 2; ++n) {
            const int c = col0 + wc * 32 + n * 16 + (lane & 15);
            const float v = (acc[m][n][q] + e * a.prox[(size_t)r * DD + c]) * z;
            const size_t o = (size_t)r * DD + c;
            a.M1h[o] = hif(v); a.M1l[o] = lof(v);
          }
        }
      }
  }
}

// h1 = relu(M1@W1 + b1); also emit split-transposed proxy rows. u in [0,144)
__device__ void dv_h1(int u, const FA& a, f16* lds)
{
  f32x4 acc[2][2] = {};
  const int t = threadIdx.x, lane = t & 63, w = t >> 6, wr = w >> 1, wc = w & 1;
  const int row0 = (u >> 3) * 64, col0 = (u & 7) * 64;
  mgemm_core(a.M1h, a.M1l, a.W1th, a.W1tl, DD, row0, col0, lds, acc);
#pragma unroll
  for (int m = 0; m < 2; ++m)
#pragma unroll
    for (int q = 0; q < 4; ++q) {
      const int r = row0 + wr * 32 + m * 16 + (lane >> 4) * 4 + q;
      if (r >= NN) continue;
#pragma unroll
      for (int n = 0; n < 2; ++n) {
        const int c = col0 + wc * 32 + n * 16 + (lane & 15);
        const float v = fmaxf(acc[m][n][q] + a.b1[c], 0.f);
        a.h1[(size_t)r * DD + c] = v;
        if (r < 128) {                       // B of agg2: zero-fill k-pad rows
          const size_t o = (size_t)c * 128 + r;
          f16 hh = (f16)0.f, ll = (f16)0.f;
          if (r < PP) { hh = hif(v); ll = lof(v); }
          a.h1pth[o] = hh; a.h1ptl[o] = ll;
        }
      }
    }
}

// layer-2 aggregation (sample dsts only). u in [0,128)
__device__ void dv_agg2(int u, const FA& a, f16* lds)
{
  f32x4 acc[2][2] = {};
  const int t = threadIdx.x, lane = t & 63, w = t >> 6, wr = w >> 1, wc = w & 1;
  const int row0 = (u >> 3) * 64, col0 = (u & 7) * 64;
  mgemm_core(a.Es2h, a.Es2l, a.h1pth, a.h1ptl, 128, row0, col0, lds, acc);
#pragma unroll
  for (int m = 0; m < 2; ++m)
#pragma unroll
    for (int q = 0; q < 4; ++q) {
      const int r = row0 + wr * 32 + m * 16 + (lane >> 4) * 4 + q;
      const float e = a.esS2[r], z = a.izS2[r];
#pragma unroll
      for (int n = 0; n < 2; ++n) {
        const int c = col0 + wc * 32 + n * 16 + (lane & 15);
        const float v = (acc[m][n][q] + e * a.h1[(size_t)(PP + r) * DD + c]) * z;
        const size_t o = (size_t)r * DD + c;
        a.M2h[o] = hif(v); a.M2l[o] = lof(v);
      }
    }
}

// h2 = relu(M2@W2 + b2) -> d_out (fp32) + split for fc. u in [0,128)
__device__ void dv_h2(int u, const FA& a, f16* lds)
{
  f32x4 acc[2][2] = {};
  const int t = threadIdx.x, lane = t & 63, w = t >> 6, wr = w >> 1, wc = w & 1;
  const int row0 = (u >> 3) * 64, col0 = (u & 7) * 64;
  mgemm_core(a.M2h, a.M2l, a.W2th, a.W2tl, DD, row0, col0, lds, acc);
#pragma unroll
  for (int m = 0; m < 2; ++m)
#pragma unroll
    for (int q = 0; q < 4; ++q) {
      const int r = row0 + wr * 32 + m * 16 + (lane >> 4) * 4 + q;
#pragma unroll
      for (int n = 0; n < 2; ++n) {
        const int c = col0 + wc * 32 + n * 16 + (lane & 15);
        const float v = fmaxf(acc[m][n][q] + a.b2[c], 0.f);
        const size_t o = (size_t)r * DD + c;
        a.h2s[o] = v;
        a.h2h[o] = hif(v); a.h2l[o] = lof(v);
      }
    }
}

// preds = h2 @ fcw + fcb. u in [0,32)
__device__ void dv_fc(int u, const FA& a, f16* lds)
{
  f32x4 acc[2][2] = {};
  const int t = threadIdx.x, lane = t & 63, w = t >> 6, wr = w >> 1, wc = w & 1;
  const int row0 = (u >> 1) * 64, col0 = (u & 1) * 64;
  mgemm_core(a.h2h, a.h2l, a.fwth, a.fwtl, DD, row0, col0, lds, acc);
#pragma unroll
  for (int m = 0; m < 2; ++m)
#pragma unroll
    for (int q = 0; q < 4; ++q) {
      const int r = row0 + wr * 32 + m * 16 + (lane >> 4) * 4 + q;
#pragma unroll
      for (int n = 0; n < 2; ++n) {
        const int c = col0 + wc * 32 + n * 16 + (lane & 15);
        if (c < CC) a.out[(size_t)r * CC + c] = acc[m][n][q] + a.fcb[c];
      }
    }
}

// =================== fused cooperative kernel ==============================
__global__ __launch_bounds__(NTHR) void fused_k(FA a)
{
  cg::grid_group g = cg::this_grid();
  __shared__ __align__(16) f16 lds[10240];
  __shared__ float red[4];
  f16 (*th)[72] = (f16(*)[72])lds;
  f16 (*tl)[72] = (f16(*)[72])(lds + 4608);

  for (int u = blockIdx.x; u < 544; u += gridDim.x) {   // P0 prep
    dv_prep(u, a, th, tl);
    __syncthreads();
  }
  g.sync();
  for (int u = blockIdx.x; u < 281; u += gridDim.x)     // P1 lvec1
    dv_lvec(u, a.prox, a.x, PP, a.v1s, a.v1d, a.ls1, a.ld1);
  g.sync();
  for (int u = blockIdx.x; u < 384; u += gridDim.x) {   // P2 alpha1
    dv_alpha(u, a.ls1, a.ld1, a.Es1h, a.Es1l, a.esS1, a.izS1,
             a.Eph, a.Epl, a.esP, a.izP, red);
    __syncthreads();
  }
  g.sync();
  for (int u = blockIdx.x; u < 144; u += gridDim.x)     // P3 agg1
    dv_agg1(u, a, lds);
  g.sync();
  for (int u = blockIdx.x; u < 144; u += gridDim.x)     // P4 h1
    dv_h1(u, a, lds);
  g.sync();
  for (int u = blockIdx.x; u < 281; u += gridDim.x)     // P5 lvec2
    dv_lvec(u, a.h1, a.h1, NN, a.v2s, a.v2d, a.ls2, a.ld2);
  g.sync();
  for (int u = blockIdx.x; u < 256; u += gridDim.x) {   // P6 alpha2 (samples)
    dv_alpha(u, a.ls2, a.ld2, a.Es2h, a.Es2l, a.esS2, a.izS2,
             a.Eph, a.Epl, a.esP, a.izP, red);
    __syncthreads();
  }
  g.sync();
  for (int u = blockIdx.x; u < 128; u += gridDim.x)     // P7 agg2
    dv_agg2(u, a, lds);
  g.sync();
  for (int u = blockIdx.x; u < 128; u += gridDim.x)     // P8 h2
    dv_h2(u, a, lds);
  g.sync();
  for (int u = blockIdx.x; u < 32; u += gridDim.x)      // P9 fc
    dv_fc(u, a, lds);
}

// =================== fallback (non-cooperative) wrappers ===================
__global__ __launch_bounds__(NTHR) void prep_k(FA a) {
  __shared__ f16 th[64][72];
  __shared__ f16 tl[64][72];
  dv_prep(blockIdx.x, a, th, tl);
}
__global__ __launch_bounds__(NTHR) void lvec_k(FA a, int layer) {
  if (layer == 1) dv_lvec(blockIdx.x, a.prox, a.x, PP, a.v1s, a.v1d, a.ls1, a.ld1);
  else            dv_lvec(blockIdx.x, a.h1, a.h1, NN, a.v2s, a.v2d, a.ls2, a.ld2);
}
__global__ __launch_bounds__(NTHR) void alpha_k(FA a, int layer) {
  __shared__ float red[4];
  if (layer == 1)
    dv_alpha(blockIdx.x, a.ls1, a.ld1, a.Es1h, a.Es1l, a.esS1, a.izS1,
             a.Eph, a.Epl, a.esP, a.izP, red);
  else
    dv_alpha(blockIdx.x, a.ls2, a.ld2, a.Es2h, a.Es2l, a.esS2, a.izS2,
             a.Eph, a.Epl, a.esP, a.izP, red);
}
__global__ __launch_bounds__(NTHR) void agg1_k(FA a) {
  __shared__ __align__(16) f16 lds[10240];
  dv_agg1(blockIdx.x, a, lds);
}
__global__ __launch_bounds__(NTHR) void h1_k(FA a) {
  __shared__ __align__(16) f16 lds[10240];
  dv_h1(blockIdx.x, a, lds);
}
__global__ __launch_bounds__(NTHR) void agg2_k(FA a) {
  __shared__ __align__(16) f16 lds[10240];
  dv_agg2(blockIdx.x, a, lds);
}
__global__ __launch_bounds__(NTHR) void h2_k(FA a) {
  __shared__ __align__(16) f16 lds[10240];
  dv_h2(blockIdx.x, a, lds);
}
__global__ __launch_bounds__(NTHR) void fc_k(FA a) {
  __shared__ __align__(16) f16 lds[10240];
  dv_fc(blockIdx.x, a, lds);
}

extern "C" void kernel_launch(void* const* d_in, const int* in_sizes, int n_in,
                              void* d_out, int out_size, void* d_ws, size_t ws_size,
                              hipStream_t stream)
{
  FA a;
  a.x    = (const float*)d_in[0];
  a.prox = (const float*)d_in[1];
  a.W1   = (const float*)d_in[2];
  a.as1  = (const float*)d_in[3];
  a.ad1  = (const float*)d_in[4];
  a.b1   = (const float*)d_in[5];
  a.W2   = (const float*)d_in[6];
  a.as2  = (const float*)d_in[7];
  a.ad2  = (const float*)d_in[8];
  a.b2   = (const float*)d_in[9];
  a.fcw  = (const float*)d_in[10];
  a.fcb  = (const float*)d_in[11];
  a.out  = (float*)d_out;

  // fp32 workspace
  float* F = (float*)d_ws;
  a.h1   = F; F += (size_t)NN * DD;
  a.ls1  = F; F += 1152;
  a.ld1  = F; F += 1152;
  a.ls2  = F; F += 1152;
  a.ld2  = F; F += 1152;
  a.v1s  = F; F += DD;
  a.v1d  = F; F += DD;
  a.v2s  = F; F += DD;
  a.v2d  = F; F += DD;
  a.esS1 = F; F += NS;
  a.izS1 = F; F += NS;
  a.esS2 = F; F += NS;
  a.izS2 = F; F += NS;
  a.esP  = F; F += 128;
  a.izP  = F; F += 128;
  // f16 split workspace (all bases 16B aligned; sizes multiples of 8 halves)
  f16* H = (f16*)F;
  a.M1h  = H; H += (size_t)1152 * DD;   // rows: 100 prox + 1024 samp + pad
  a.M1l  = H; H += (size_t)1152 * DD;
  a.M2h  = H; H += (size_t)NS * DD;
  a.M2l  = H; H += (size_t)NS * DD;
  a.Es1h = H; H += (size_t)NS * 128;
  a.Es1l = H; H += (size_t)NS * 128;
  a.Es2h = H; H += (size_t)NS * 128;
  a.Es2l = H; H += (size_t)NS * 128;
  a.Eph  = H; H += (size_t)128 * NS;
  a.Epl  = H; H += (size_t)128 * NS;
  a.xth  = H; H += (size_t)DD * NS;     // x^T  [512][1024]
  a.xtl  = H; H += (size_t)DD * NS;
  a.pth  = H; H += (size_t)DD * 128;    // prox^T [512][128] (k-pad zeroed)
  a.ptl  = H; H += (size_t)DD * 128;
  a.W1th = H; H += (size_t)DD * DD;     // W1^T [512][512]
  a.W1tl = H; H += (size_t)DD * DD;
  a.W2th = H; H += (size_t)DD * DD;
  a.W2tl = H; H += (size_t)DD * DD;
  a.fwth = H; H += (size_t)128 * DD;    // fcw^T [128][512] (k-pad zeroed)
  a.fwtl = H; H += (size_t)128 * DD;
  a.h2h  = H; H += (size_t)NS * DD;
  a.h2l  = H; H += (size_t)NS * DD;
  a.h1pth = H; H += (size_t)DD * 128;   // h1 proxy rows ^T [512][128]
  a.h1ptl = H; H += (size_t)DD * 128;
  a.h2s  = a.out + (size_t)NS * CC;     // layer-2 sample out in d_out

  dim3 blk(NTHR);
  void* params[] = { (void*)&a };
  hipError_t err = hipLaunchCooperativeKernel(
      (const void*)fused_k, dim3(256), blk, params, 0, stream);
  if (err != hipSuccess) {
    // fallback: original 10-launch sequence (same math)
    prep_k <<<dim3(544), blk, 0, stream>>>(a);
    lvec_k <<<dim3(281), blk, 0, stream>>>(a, 1);
    alpha_k<<<dim3(384), blk, 0, stream>>>(a, 1);
    agg1_k <<<dim3(144), blk, 0, stream>>>(a);
    h1_k   <<<dim3(144), blk, 0, stream>>>(a);
    lvec_k <<<dim3(281), blk, 0, stream>>>(a, 2);
    alpha_k<<<dim3(256), blk, 0, stream>>>(a, 2);
    agg2_k <<<dim3(128), blk, 0, stream>>>(a);
    h2_k   <<<dim3(128), blk, 0, stream>>>(a);
    fc_k   <<<dim3(32),  blk, 0, stream>>>(a);
  }
}